// Round 3
// baseline (1182.145 us; speedup 1.0000x reference)
//
#include <hip/hip_runtime.h>
#include <math.h>

typedef unsigned int u32;
typedef unsigned short u16;
typedef __attribute__((ext_vector_type(8))) short short8;
typedef __attribute__((ext_vector_type(4))) float f32x4;
typedef __attribute__((ext_vector_type(4))) u32 u32x4;

#define NB 16
#define NS 128
#define NTW 16
#define NEDIM 300
#define NCED 50
#define NCH 50
#define NTAGS 10
#define XDIM 400
#define NWIN 1928

__device__ __forceinline__ float sigf(float x){ return 1.0f/(1.0f+__expf(-x)); }
__device__ __forceinline__ float tanhfast(float x){
  float e = __expf(2.0f*x);
  return 1.0f - 2.0f/(e + 1.0f);
}
__device__ __forceinline__ u16 f2bu(float f){
  u32 u = __float_as_uint(f);
  return (u16)((u + 0x7fffu + ((u>>16)&1u))>>16);
}
__device__ __forceinline__ float bf2f(u16 x){ return __uint_as_float(((u32)x)<<16); }

// ---------------- embedding gather: x[:, 0:300] ----------------
__global__ void k_embed(const float* __restrict__ emb, const int* __restrict__ sent,
                        float* __restrict__ x){
  int n = blockIdx.x;                       // 0..2047 (b*128+s)
  int row = sent[n];
  const float* src = emb + (size_t)row*NEDIM;
  float* dst = x + (size_t)n*XDIM;
  for (int d = threadIdx.x; d < NEDIM; d += blockDim.x) dst[d] = src[d];
}

// ---------------- char BiLSTM (final hidden only) -> x[:, 300:400] ----------------
__global__ void k_char(const float* __restrict__ char_emb,
                       const float* __restrict__ wih_f, const float* __restrict__ whh_f, const float* __restrict__ b_f,
                       const float* __restrict__ wih_b, const float* __restrict__ whh_b, const float* __restrict__ b_b,
                       const int* __restrict__ wchars, const int* __restrict__ wlens,
                       const int* __restrict__ slens, float* __restrict__ x){
  const int dir = blockIdx.y;
  const int tid = threadIdx.x;
  __shared__ u16 wih_l[200*NCED];
  __shared__ u16 whh_l[200*NCED];
  __shared__ float z_l[200];
  __shared__ float h_l[NCH];
  const float* wih = dir ? wih_b : wih_f;
  const float* whh = dir ? whh_b : whh_f;
  const float* bp  = dir ? b_b   : b_f;
  for (int i = tid; i < 200*NCED; i += 256){
    wih_l[i] = f2bu(wih[i]);
    whh_l[i] = f2bu(whh[i]);
  }
  float bias = (tid < 200) ? bp[tid] : 0.f;
  __syncthreads();
  for (int w = 0; w < 4; ++w){
    int n = blockIdx.x*4 + w;
    int b = n >> 7, s = n & 127;
    int len = wlens[n];                    // in [1,16]
    float c = 0.f, hcur = 0.f;
    if (tid < NCH) h_l[tid] = 0.f;
    __syncthreads();
    for (int t = 0; t < len; ++t){
      int tt = dir ? (len-1-t) : t;
      int ch = wchars[n*NTW + tt];
      if (tid < 200){
        const float* xe = char_emb + ch*NCED;
        const u16* wr = wih_l + tid*NCED;
        const u16* ur = whh_l + tid*NCED;
        float acc = bias;
        #pragma unroll 10
        for (int k = 0; k < NCED; ++k){
          float wv = __uint_as_float(((u32)wr[k])<<16);
          float uv = __uint_as_float(((u32)ur[k])<<16);
          acc += wv*xe[k] + uv*h_l[k];
        }
        z_l[tid] = acc;
      }
      __syncthreads();
      if (tid < NCH){
        float gi = sigf(z_l[tid]);
        float gf = sigf(z_l[NCH+tid]);
        float gg = tanhf(z_l[2*NCH+tid]);
        float go = sigf(z_l[3*NCH+tid]);
        c = gf*c + gi*gg;
        hcur = go*tanhf(c);
        h_l[tid] = hcur;
      }
      __syncthreads();
    }
    if (tid < NCH){
      float v = (s < slens[b]) ? hcur : 0.f;   // pad_sequence zeroing
      x[(size_t)n*XDIM + NEDIM + dir*NCH + tid] = v;
    }
  }
}

// ---------------- xg = bf16(x @ wih^T + b) written in MFMA-fragment/t-major layout ----
// xgT element index: ((dir*128 + t)*512 + tid)*32 + p*16 + gg*8 + u2*4 + r
//   where for gate g: p=g&1, gg=g>>1;  tid = w*64 + q*16 + jc;  b = q*4+r;
//   j (within dir) = g*256 + (2w+u2)*16 + jc;  t = dir ? len_b-1-row : row.
__global__ void k_wxg(const float* __restrict__ x,
                      const float* __restrict__ wih_f, const float* __restrict__ wih_b,
                      const float* __restrict__ bw_f, const float* __restrict__ bw_b,
                      const int* __restrict__ slens,
                      u16* __restrict__ xgT){
  __shared__ float As[16][65];
  __shared__ float Bs[16][65];
  int tid = threadIdx.x;
  int tx = tid & 15, ty = tid >> 4;
  int n0 = blockIdx.x * 64;        // output col (dir*1024 + j)
  int m0 = blockIdx.y * 64;        // row (b*128+s)
  int dir = n0 >> 10;
  int j0  = n0 & 1023;
  const float* wih = dir ? wih_b : wih_f;
  const float* bw  = dir ? bw_b  : bw_f;
  float acc[4][4] = {};
  for (int k0 = 0; k0 < 400; k0 += 16){
    #pragma unroll
    for (int i = 0; i < 4; ++i){
      int e = tid + i*256;
      int kk = e & 15, m = e >> 4;
      As[kk][m] = x[(m0+m)*XDIM + k0 + kk];
      Bs[kk][m] = wih[(j0+m)*XDIM + k0 + kk];
    }
    __syncthreads();
    #pragma unroll
    for (int kk = 0; kk < 16; ++kk){
      float av[4], bv[4];
      #pragma unroll
      for (int i=0;i<4;++i) av[i] = As[kk][ty*4+i];
      #pragma unroll
      for (int j=0;j<4;++j) bv[j] = Bs[kk][tx*4+j];
      #pragma unroll
      for (int i=0;i<4;++i)
        #pragma unroll
        for (int j=0;j<4;++j) acc[i][j] = fmaf(av[i], bv[j], acc[i][j]);
    }
    __syncthreads();
  }
  int b_ = m0 >> 7;                 // batch, constant per block
  int len = slens[b_];
  int q_ = b_ >> 2, r_ = b_ & 3;
  #pragma unroll
  for (int i=0;i<4;++i){
    int m = m0 + ty*4 + i;
    int row = m & 127;
    int t = dir ? (len-1-row) : row;
    if (t >= 0){
      #pragma unroll
      for (int j=0;j<4;++j){
        int jj = j0 + tx*4 + j;          // j within dir, 0..1023
        float v = acc[i][j] + bw[jj];
        int g = jj >> 8, u = jj & 255;
        int ut = u >> 4, jc_ = u & 15;
        int w_ = ut >> 1, u2_ = ut & 1;
        int p_ = g & 1, gg_ = g >> 1;
        int tid_ = w_*64 + q_*16 + jc_;
        size_t e = ((size_t)((dir<<7) + t)*512 + tid_)*32 + p_*16 + gg_*8 + u2_*4 + r_;
        xgT[e] = f2bu(v);
      }
    }
  }
}

// ---------------- word BiLSTM recurrence: 2 blocks (one per dir), weights CU-resident ----
// 8 waves; wave w owns u-tiles {2w,2w+1} x all 4 gates. whh: 6 K-tiles in VGPRs,
// 2 K-tiles in LDS. H double-buffered in LDS. One barrier per step, no inter-block sync.
__global__ __launch_bounds__(512, 2) void k_wlstm3(
    const float* __restrict__ whh_f, const float* __restrict__ whh_b,
    const u16* __restrict__ xgT, const int* __restrict__ slens,
    float* __restrict__ out){
  const int dir  = blockIdx.x;
  const int tid  = threadIdx.x;
  const int lane = tid & 63;
  const int w    = tid >> 6;        // wave 0..7
  const int q    = lane >> 4;       // 0..3
  const int jc   = lane & 15;

  __shared__ __align__(16) u32 WL[2][64][64][4];   // 128 KB: K-tiles 6,7 for all 64 j-tiles
  __shared__ __align__(16) u16 Hs[2][16][256];     // 16 KB: H double-buffered

  const float* whh = dir ? whh_b : whh_f;

  int lenr[4];
  #pragma unroll
  for (int r=0;r<4;++r) lenr[r] = slens[q*4+r];

  // ---- register-resident weight fragments: Wf[g][u2][kt], kt 0..5 ----
  short8 Wf[4][2][6];
  #pragma unroll
  for (int g=0; g<4; ++g){
    #pragma unroll
    for (int u2=0; u2<2; ++u2){
      int j = g*256 + (2*w+u2)*16 + jc;
      const float* wr = whh + (size_t)j*256;
      #pragma unroll
      for (int kt=0; kt<6; ++kt){
        int k0 = kt*32 + q*8;
        f32x4 w0 = *(const f32x4*)(wr + k0);
        f32x4 w1 = *(const f32x4*)(wr + k0 + 4);
        short8 s;
        s[0]=(short)f2bu(w0[0]); s[1]=(short)f2bu(w0[1]);
        s[2]=(short)f2bu(w0[2]); s[3]=(short)f2bu(w0[3]);
        s[4]=(short)f2bu(w1[0]); s[5]=(short)f2bu(w1[1]);
        s[6]=(short)f2bu(w1[2]); s[7]=(short)f2bu(w1[3]);
        Wf[g][u2][kt] = s;
      }
    }
  }

  // ---- LDS weight fill: K-tiles 6,7 ----
  for (int idx = tid; idx < 2*64*64; idx += 512){
    int kt2 = idx >> 12; int rem = idx & 4095;
    int jt = rem >> 6;   int ln = rem & 63;
    int g = jt >> 4, ut = jt & 15;
    int j = g*256 + ut*16 + (ln & 15);
    int k0 = (6+kt2)*32 + (ln>>4)*8;
    const float* wr = whh + (size_t)j*256 + k0;
    f32x4 w0 = *(const f32x4*)(wr);
    f32x4 w1 = *(const f32x4*)(wr + 4);
    WL[kt2][jt][ln][0] = ((u32)f2bu(w0[1])<<16) | f2bu(w0[0]);
    WL[kt2][jt][ln][1] = ((u32)f2bu(w0[3])<<16) | f2bu(w0[2]);
    WL[kt2][jt][ln][2] = ((u32)f2bu(w1[1])<<16) | f2bu(w1[0]);
    WL[kt2][jt][ln][3] = ((u32)f2bu(w1[3])<<16) | f2bu(w1[2]);
  }

  // zero H buffer 0
  for (int i = tid; i < 2048; i += 512) ((u32*)Hs[0])[i] = 0u;
  __syncthreads();

  float c[2][4] = {{0.f,0.f,0.f,0.f},{0.f,0.f,0.f,0.f}};
  float P[2][4];
  const u16* xbase = xgT + ((size_t)(dir*128)*512 + tid)*32;
  int cur = 0;

  for (int t = 0; t < 128; ++t){
    // x pre-activations for this step: 64 B linear per thread (hides under K-loop)
    const u16* xp = xbase + (size_t)t*16384;
    u32x4 xv[4];
    #pragma unroll
    for (int i=0;i<4;++i) xv[i] = *(const u32x4*)(xp + i*8);

    const char* Hc = (const char*)Hs[cur];
    int nxt = cur ^ 1;
    u16* Hn = (u16*)Hs[nxt];

    #pragma unroll
    for (int p = 0; p < 2; ++p){
      // phase p handles gates {p, p+2}: p0 -> i(0),g(2); p1 -> f(1),o(3)
      f32x4 a[2][2] = {{{0.f,0.f,0.f,0.f},{0.f,0.f,0.f,0.f}},
                       {{0.f,0.f,0.f,0.f},{0.f,0.f,0.f,0.f}}};
      #pragma unroll
      for (int kt = 0; kt < 8; ++kt){
        short8 af = *(const short8*)(Hc + jc*512 + ((kt*64 + q*16) ^ ((jc&7)<<4)));
        if (kt < 6){
          #pragma unroll
          for (int gg=0; gg<2; ++gg){
            #pragma unroll
            for (int u2=0; u2<2; ++u2)
              a[gg][u2] = __builtin_amdgcn_mfma_f32_16x16x32_bf16(af, Wf[gg*2+p][u2][kt], a[gg][u2], 0,0,0);
          }
        } else {
          #pragma unroll
          for (int gg=0; gg<2; ++gg){
            #pragma unroll
            for (int u2=0; u2<2; ++u2){
              short8 wl = *(const short8*)&WL[kt-6][(gg*2+p)*16 + 2*w+u2][lane][0];
              a[gg][u2] = __builtin_amdgcn_mfma_f32_16x16x32_bf16(af, wl, a[gg][u2], 0,0,0);
            }
          }
        }
      }
      // combine
      #pragma unroll
      for (int u2=0; u2<2; ++u2){
        #pragma unroll
        for (int r=0; r<4; ++r){
          float x0 = bf2f((u16)(xv[p*2+0][(u2*4+r)>>1] >> (((u2*4+r)&1)*16)));
          float x1 = bf2f((u16)(xv[p*2+1][(u2*4+r)>>1] >> (((u2*4+r)&1)*16)));
          if (p == 0){
            float zi = a[0][u2][r] + x0;           // gate i
            float zg = a[1][u2][r] + x1;           // gate g
            P[u2][r] = sigf(zi) * tanhfast(zg);
          } else {
            float zf = a[0][u2][r] + x0;           // gate f
            float zo = a[1][u2][r] + x1;           // gate o
            float cc = sigf(zf)*c[u2][r] + P[u2][r];
            c[u2][r] = cc;
            float h = sigf(zo)*tanhfast(cc);
            int b_ = q*4 + r;
            int u_ = (2*w+u2)*16 + jc;
            Hn[b_*256 + (((u_*2) ^ ((b_&7)<<4))>>1)] = f2bu(h);
            if (t < lenr[r]){
              int row = dir ? (lenr[r]-1-t) : t;
              out[((b_<<7)+row)*512 + dir*256 + u_] = h;
            }
          }
        }
      }
    }
    __syncthreads();
    cur = nxt;
  }
}

// ---------------- prefix sums over s ----------------
__global__ void k_csum(const float* __restrict__ out, float* __restrict__ csum){
  int gid = blockIdx.x*256 + threadIdx.x;   // 8192 = 16*512
  int b = gid >> 9, d = gid & 511;
  float run = 0.f;
  csum[(b*129)*512 + d] = 0.f;
  for (int s = 0; s < 128; ++s){
    run += out[((b<<7)+s)*512 + d];
    csum[(b*129 + s + 1)*512 + d] = run;
  }
}

// ---------------- per-position first/last classifier terms ----------------
__global__ void k_ac(const float* __restrict__ out, const float* __restrict__ clf_w,
                     float* __restrict__ A, float* __restrict__ Cm){
  int gid = blockIdx.x*256 + threadIdx.x;   // 20480 = 2048*10
  int bs = gid / 10, tag = gid % 10;
  const float* o  = out + bs*512;
  const float* w1 = clf_w + tag*1536;       // "first" block
  const float* w3 = w1 + 1024;              // "last" block
  float a=0.f, cc=0.f;
  for (int d = 0; d < 512; ++d){
    float vv = fmaxf(o[d], 0.f);
    a  = fmaf(vv, w1[d], a);
    cc = fmaf(vv, w3[d], cc);
  }
  A[gid] = a; Cm[gid] = cc;
}

// ---------------- window classifier: wave per (n,b) ----------------
__global__ void k_clf(const float* __restrict__ csum, const float* __restrict__ clf_w,
                      const float* __restrict__ clf_b, const float* __restrict__ A,
                      const float* __restrict__ Cm, float* __restrict__ dout){
  __shared__ float w2_l[NTAGS*512];
  int tid = threadIdx.x;
  for (int i = tid; i < NTAGS*512; i += 256){
    int tag = i >> 9, d = i & 511;
    w2_l[i] = clf_w[tag*1536 + 512 + d];    // "mean" block
  }
  __syncthreads();
  int qq = blockIdx.x*4 + (tid >> 6);       // 0..30847
  int lane = tid & 63;
  int n = qq >> 4, b = qq & 15;
  int rem = n, r = 1;
  while (rem >= 129 - r){ rem -= 129 - r; ++r; }
  int s0 = rem, s1 = s0 + r - 1;
  float invr = 1.0f / (float)r;
  int d0 = lane*8;
  const float* c0 = csum + (b*129 + s0    )*512 + d0;
  const float* c1 = csum + (b*129 + s0 + r)*512 + d0;
  float m[8];
  #pragma unroll
  for (int i=0;i<8;++i) m[i] = fmaxf((c1[i]-c0[i])*invr, 0.f);
  float p[10];
  #pragma unroll
  for (int tag=0; tag<NTAGS; ++tag){
    const float* wv = w2_l + tag*512 + d0;
    float s = 0.f;
    #pragma unroll
    for (int i=0;i<8;++i) s = fmaf(m[i], wv[i], s);
    #pragma unroll
    for (int off=32; off>=1; off>>=1) s += __shfl_xor(s, off);
    p[tag] = s;
  }
  if (lane == 0){
    #pragma unroll
    for (int tag=0; tag<NTAGS; ++tag){
      float vv = p[tag] + A[(b*128+s0)*10+tag] + Cm[(b*128+s1)*10+tag] + clf_b[tag];
      dout[b*(NTAGS*NWIN) + tag*NWIN + n] = vv;
    }
  }
}

extern "C" void kernel_launch(void* const* d_in, const int* in_sizes, int n_in,
                              void* d_out, int out_size, void* d_ws, size_t ws_size,
                              hipStream_t stream){
  (void)in_sizes; (void)n_in; (void)out_size; (void)ws_size;
  const float* emb      = (const float*)d_in[0];
  const float* char_emb = (const float*)d_in[1];
  const float* c_wih_f  = (const float*)d_in[2];
  const float* c_whh_f  = (const float*)d_in[3];
  const float* c_b_f    = (const float*)d_in[4];
  const float* c_wih_b  = (const float*)d_in[5];
  const float* c_whh_b  = (const float*)d_in[6];
  const float* c_b_b    = (const float*)d_in[7];
  const float* w_wih_f  = (const float*)d_in[8];
  const float* w_whh_f  = (const float*)d_in[9];
  const float* w_b_f    = (const float*)d_in[10];
  const float* w_wih_b  = (const float*)d_in[11];
  const float* w_whh_b  = (const float*)d_in[12];
  const float* w_b_b    = (const float*)d_in[13];
  const float* clf_w    = (const float*)d_in[14];
  const float* clf_b    = (const float*)d_in[15];
  const int* sentences  = (const int*)d_in[16];
  const int* slens      = (const int*)d_in[17];
  const int* wchars     = (const int*)d_in[18];
  const int* wlens      = (const int*)d_in[19];

  float* ws   = (float*)d_ws;
  float* x    = ws;                       // 819,200 f
  u16*  xgT   = (u16*)(ws + 819200);      // 4,194,304 u16 = 2,097,152 f
  float* outb = ws + 2916352;             // 1,048,576 f
  float* csum = ws + 3964928;             // 1,056,768 f
  float* A    = ws + 5021696;             // 20,480 f
  float* Cm   = ws + 5042176;             // 20,480 f

  hipMemsetAsync(outb, 0, (size_t)2048*512*sizeof(float), stream);
  k_embed<<<2048, 256, 0, stream>>>(emb, sentences, x);
  k_char<<<dim3(512,2), 256, 0, stream>>>(char_emb, c_wih_f, c_whh_f, c_b_f,
                                          c_wih_b, c_whh_b, c_b_b,
                                          wchars, wlens, slens, x);
  k_wxg<<<dim3(32,32), 256, 0, stream>>>(x, w_wih_f, w_wih_b, w_b_f, w_b_b, slens, xgT);
  k_wlstm3<<<2, 512, 0, stream>>>(w_whh_f, w_whh_b, xgT, slens, outb);
  k_csum<<<32, 256, 0, stream>>>(outb, csum);
  k_ac<<<80, 256, 0, stream>>>(outb, clf_w, A, Cm);
  k_clf<<<7712, 256, 0, stream>>>(csum, clf_w, clf_b, A, Cm, (float*)d_out);
}

// Round 4
// 1171.275 us; speedup vs baseline: 1.0093x; 1.0093x over previous
//
#include <hip/hip_runtime.h>
#include <math.h>

typedef unsigned int u32;
typedef unsigned short u16;
typedef __attribute__((ext_vector_type(8))) short short8;
typedef __attribute__((ext_vector_type(4))) float f32x4;
typedef __attribute__((ext_vector_type(4))) u32 u32x4;

#define NB 16
#define NS 128
#define NTW 16
#define NEDIM 300
#define NCED 50
#define NCH 50
#define NTAGS 10
#define XDIM 400
#define NWIN 1928

__device__ __forceinline__ float sigf(float x){ return 1.0f/(1.0f+__expf(-x)); }
__device__ __forceinline__ float tanhfast(float x){
  float e = __expf(2.0f*x);
  return 1.0f - 2.0f/(e + 1.0f);
}
__device__ __forceinline__ u16 f2bu(float f){
  u32 u = __float_as_uint(f);
  return (u16)((u + 0x7fffu + ((u>>16)&1u))>>16);
}
__device__ __forceinline__ float bf2f(u16 x){ return __uint_as_float(((u32)x)<<16); }

// ---------------- embedding gather: x[:, 0:300] ----------------
__global__ void k_embed(const float* __restrict__ emb, const int* __restrict__ sent,
                        float* __restrict__ x){
  int n = blockIdx.x;                       // 0..2047 (b*128+s)
  int row = sent[n];
  const float* src = emb + (size_t)row*NEDIM;
  float* dst = x + (size_t)n*XDIM;
  for (int d = threadIdx.x; d < NEDIM; d += blockDim.x) dst[d] = src[d];
}

// ---------------- char BiLSTM (final hidden only) -> x[:, 300:400] ----------------
__global__ void k_char(const float* __restrict__ char_emb,
                       const float* __restrict__ wih_f, const float* __restrict__ whh_f, const float* __restrict__ b_f,
                       const float* __restrict__ wih_b, const float* __restrict__ whh_b, const float* __restrict__ b_b,
                       const int* __restrict__ wchars, const int* __restrict__ wlens,
                       const int* __restrict__ slens, float* __restrict__ x){
  const int dir = blockIdx.y;
  const int tid = threadIdx.x;
  __shared__ u16 wih_l[200*NCED];
  __shared__ u16 whh_l[200*NCED];
  __shared__ float z_l[200];
  __shared__ float h_l[NCH];
  const float* wih = dir ? wih_b : wih_f;
  const float* whh = dir ? whh_b : whh_f;
  const float* bp  = dir ? b_b   : b_f;
  for (int i = tid; i < 200*NCED; i += 256){
    wih_l[i] = f2bu(wih[i]);
    whh_l[i] = f2bu(whh[i]);
  }
  float bias = (tid < 200) ? bp[tid] : 0.f;
  __syncthreads();
  for (int w = 0; w < 4; ++w){
    int n = blockIdx.x*4 + w;
    int b = n >> 7, s = n & 127;
    int len = wlens[n];                    // in [1,16]
    float c = 0.f, hcur = 0.f;
    if (tid < NCH) h_l[tid] = 0.f;
    __syncthreads();
    for (int t = 0; t < len; ++t){
      int tt = dir ? (len-1-t) : t;
      int ch = wchars[n*NTW + tt];
      if (tid < 200){
        const float* xe = char_emb + ch*NCED;
        const u16* wr = wih_l + tid*NCED;
        const u16* ur = whh_l + tid*NCED;
        float acc = bias;
        #pragma unroll 10
        for (int k = 0; k < NCED; ++k){
          float wv = __uint_as_float(((u32)wr[k])<<16);
          float uv = __uint_as_float(((u32)ur[k])<<16);
          acc += wv*xe[k] + uv*h_l[k];
        }
        z_l[tid] = acc;
      }
      __syncthreads();
      if (tid < NCH){
        float gi = sigf(z_l[tid]);
        float gf = sigf(z_l[NCH+tid]);
        float gg = tanhf(z_l[2*NCH+tid]);
        float go = sigf(z_l[3*NCH+tid]);
        c = gf*c + gi*gg;
        hcur = go*tanhf(c);
        h_l[tid] = hcur;
      }
      __syncthreads();
    }
    if (tid < NCH){
      float v = (s < slens[b]) ? hcur : 0.f;   // pad_sequence zeroing
      x[(size_t)n*XDIM + NEDIM + dir*NCH + tid] = v;
    }
  }
}

// ---------------- xg = bf16(x @ wih^T + b) written in MFMA-fragment/t-major layout ----
// xgT element index: ((dir*128 + t)*512 + tid)*32 + p*16 + gg*8 + u2*4 + r
//   where for gate g: p=g&1, gg=g>>1;  tid = w*64 + q*16 + jc;  b = q*4+r;
//   j (within dir) = g*256 + (2w+u2)*16 + jc;  t = dir ? len_b-1-row : row.
__global__ void k_wxg(const float* __restrict__ x,
                      const float* __restrict__ wih_f, const float* __restrict__ wih_b,
                      const float* __restrict__ bw_f, const float* __restrict__ bw_b,
                      const int* __restrict__ slens,
                      u16* __restrict__ xgT){
  __shared__ float As[16][65];
  __shared__ float Bs[16][65];
  int tid = threadIdx.x;
  int tx = tid & 15, ty = tid >> 4;
  int n0 = blockIdx.x * 64;        // output col (dir*1024 + j)
  int m0 = blockIdx.y * 64;        // row (b*128+s)
  int dir = n0 >> 10;
  int j0  = n0 & 1023;
  const float* wih = dir ? wih_b : wih_f;
  const float* bw  = dir ? bw_b  : bw_f;
  float acc[4][4] = {};
  for (int k0 = 0; k0 < 400; k0 += 16){
    #pragma unroll
    for (int i = 0; i < 4; ++i){
      int e = tid + i*256;
      int kk = e & 15, m = e >> 4;
      As[kk][m] = x[(m0+m)*XDIM + k0 + kk];
      Bs[kk][m] = wih[(j0+m)*XDIM + k0 + kk];
    }
    __syncthreads();
    #pragma unroll
    for (int kk = 0; kk < 16; ++kk){
      float av[4], bv[4];
      #pragma unroll
      for (int i=0;i<4;++i) av[i] = As[kk][ty*4+i];
      #pragma unroll
      for (int j=0;j<4;++j) bv[j] = Bs[kk][tx*4+j];
      #pragma unroll
      for (int i=0;i<4;++i)
        #pragma unroll
        for (int j=0;j<4;++j) acc[i][j] = fmaf(av[i], bv[j], acc[i][j]);
    }
    __syncthreads();
  }
  int b_ = m0 >> 7;                 // batch, constant per block
  int len = slens[b_];
  int q_ = b_ >> 2, r_ = b_ & 3;
  #pragma unroll
  for (int i=0;i<4;++i){
    int m = m0 + ty*4 + i;
    int row = m & 127;
    int t = dir ? (len-1-row) : row;
    if (t >= 0){
      #pragma unroll
      for (int j=0;j<4;++j){
        int jj = j0 + tx*4 + j;          // j within dir, 0..1023
        float v = acc[i][j] + bw[jj];
        int g = jj >> 8, u = jj & 255;
        int ut = u >> 4, jc_ = u & 15;
        int w_ = ut >> 1, u2_ = ut & 1;
        int p_ = g & 1, gg_ = g >> 1;
        int tid_ = w_*64 + q_*16 + jc_;
        size_t e = ((size_t)((dir<<7) + t)*512 + tid_)*32 + p_*16 + gg_*8 + u2_*4 + r_;
        xgT[e] = f2bu(v);
      }
    }
  }
}

// ---------------- word BiLSTM recurrence: 2 blocks (one per dir), weights CU-resident ----
// 8 waves; wave w owns u-tiles {2w,2w+1} x all 4 gates. whh: 6 K-tiles in VGPRs,
// 2 K-tiles in LDS. H double-buffered in LDS. One barrier per step.
// Register discipline: t-loop NOT unrolled; two gate-phases with per-phase
// accumulators; phase-1 x loaded at phase-1 start (L1 hit: lines pulled by
// phase-0 load); lengths packed 4x8b in one reg. Peak live ~250 <= 256.
__global__ __launch_bounds__(512, 2) void k_wlstm4(
    const float* __restrict__ whh_f, const float* __restrict__ whh_b,
    const u16* __restrict__ xgT, const int* __restrict__ slens,
    float* __restrict__ out){
  const int dir  = blockIdx.x;
  const int tid  = threadIdx.x;
  const int lane = tid & 63;
  const int w    = tid >> 6;        // wave 0..7
  const int q    = lane >> 4;       // 0..3
  const int jc   = lane & 15;

  __shared__ __align__(16) u32 WL[2][64][64][4];   // 128 KB: K-tiles 6,7 for all 64 j-tiles
  __shared__ __align__(16) u16 Hs[2][16][256];     // 16 KB: H double-buffered

  const float* whh = dir ? whh_b : whh_f;

  // packed lengths for this thread's 4 batches (b = q*4+r), 8 bits each
  u32 lens = 0;
  #pragma unroll
  for (int r=0;r<4;++r) lens |= ((u32)slens[q*4+r]) << (8*r);

  // ---- register-resident weight fragments: Wf[g][u2][kt], kt 0..5 ----
  short8 Wf[4][2][6];
  #pragma unroll
  for (int g=0; g<4; ++g){
    #pragma unroll
    for (int u2=0; u2<2; ++u2){
      int j = g*256 + (2*w+u2)*16 + jc;
      const float* wr = whh + (size_t)j*256;
      #pragma unroll
      for (int kt=0; kt<6; ++kt){
        int k0 = kt*32 + q*8;
        f32x4 w0 = *(const f32x4*)(wr + k0);
        f32x4 w1 = *(const f32x4*)(wr + k0 + 4);
        short8 s;
        s[0]=(short)f2bu(w0[0]); s[1]=(short)f2bu(w0[1]);
        s[2]=(short)f2bu(w0[2]); s[3]=(short)f2bu(w0[3]);
        s[4]=(short)f2bu(w1[0]); s[5]=(short)f2bu(w1[1]);
        s[6]=(short)f2bu(w1[2]); s[7]=(short)f2bu(w1[3]);
        Wf[g][u2][kt] = s;
      }
    }
  }

  // ---- LDS weight fill: K-tiles 6,7 ----
  for (int idx = tid; idx < 2*64*64; idx += 512){
    int kt2 = idx >> 12; int rem = idx & 4095;
    int jt = rem >> 6;   int ln = rem & 63;
    int g = jt >> 4, ut = jt & 15;
    int j = g*256 + ut*16 + (ln & 15);
    int k0 = (6+kt2)*32 + (ln>>4)*8;
    const float* wr = whh + (size_t)j*256 + k0;
    f32x4 w0 = *(const f32x4*)(wr);
    f32x4 w1 = *(const f32x4*)(wr + 4);
    WL[kt2][jt][ln][0] = ((u32)f2bu(w0[1])<<16) | f2bu(w0[0]);
    WL[kt2][jt][ln][1] = ((u32)f2bu(w0[3])<<16) | f2bu(w0[2]);
    WL[kt2][jt][ln][2] = ((u32)f2bu(w1[1])<<16) | f2bu(w1[0]);
    WL[kt2][jt][ln][3] = ((u32)f2bu(w1[3])<<16) | f2bu(w1[2]);
  }

  // zero H buffer 0
  for (int i = tid; i < 2048; i += 512) ((u32*)Hs[0])[i] = 0u;
  __syncthreads();

  float c[2][4] = {{0.f,0.f,0.f,0.f},{0.f,0.f,0.f,0.f}};
  float P[2][4];
  const u16* xbase = xgT + ((size_t)(dir*128)*512 + tid)*32;
  u32 curoff = 0;                       // byte offset of current H buffer (0 or 8192)

  #pragma clang loop unroll(disable)
  for (int t = 0; t < 128; ++t){
    const u16* xp = xbase + t*16384;
    // phase-0 x (gates i at +0, g at +8 elems): issue early, hides under MFMA
    u32x4 xi = *(const u32x4*)(xp);
    u32x4 xg = *(const u32x4*)(xp + 8);

    const char* Hc = ((const char*)Hs) + curoff;
    u16* Hn = (u16*)(((char*)Hs) + (curoff ^ 8192));

    // ---- phase 0: gates i (0) and g (2) ----
    {
      f32x4 a00={0.f,0.f,0.f,0.f}, a01={0.f,0.f,0.f,0.f};
      f32x4 a10={0.f,0.f,0.f,0.f}, a11={0.f,0.f,0.f,0.f};
      #pragma unroll
      for (int kt = 0; kt < 8; ++kt){
        short8 af = *(const short8*)(Hc + jc*512 + ((kt*64 + q*16) ^ ((jc&7)<<4)));
        if (kt < 6){
          a00 = __builtin_amdgcn_mfma_f32_16x16x32_bf16(af, Wf[0][0][kt], a00, 0,0,0);
          a01 = __builtin_amdgcn_mfma_f32_16x16x32_bf16(af, Wf[0][1][kt], a01, 0,0,0);
          a10 = __builtin_amdgcn_mfma_f32_16x16x32_bf16(af, Wf[2][0][kt], a10, 0,0,0);
          a11 = __builtin_amdgcn_mfma_f32_16x16x32_bf16(af, Wf[2][1][kt], a11, 0,0,0);
        } else {
          a00 = __builtin_amdgcn_mfma_f32_16x16x32_bf16(af, *(const short8*)&WL[kt-6][ 0 + 2*w+0][lane][0], a00, 0,0,0);
          a01 = __builtin_amdgcn_mfma_f32_16x16x32_bf16(af, *(const short8*)&WL[kt-6][ 0 + 2*w+1][lane][0], a01, 0,0,0);
          a10 = __builtin_amdgcn_mfma_f32_16x16x32_bf16(af, *(const short8*)&WL[kt-6][32 + 2*w+0][lane][0], a10, 0,0,0);
          a11 = __builtin_amdgcn_mfma_f32_16x16x32_bf16(af, *(const short8*)&WL[kt-6][32 + 2*w+1][lane][0], a11, 0,0,0);
        }
      }
      #pragma unroll
      for (int u2=0; u2<2; ++u2){
        #pragma unroll
        for (int r=0; r<4; ++r){
          int e = u2*4 + r;
          float zi = (u2 ? a01[r] : a00[r]) + bf2f((u16)(xi[e>>1] >> ((e&1)*16)));
          float zg = (u2 ? a11[r] : a10[r]) + bf2f((u16)(xg[e>>1] >> ((e&1)*16)));
          P[u2][r] = sigf(zi) * tanhfast(zg);
        }
      }
    }

    // ---- phase 1: gates f (1) and o (3) ----
    {
      // lines already in L1 from phase-0 load (same 128B lines) -> cheap
      u32x4 xf = *(const u32x4*)(xp + 16);
      u32x4 xo = *(const u32x4*)(xp + 24);
      f32x4 a00={0.f,0.f,0.f,0.f}, a01={0.f,0.f,0.f,0.f};
      f32x4 a10={0.f,0.f,0.f,0.f}, a11={0.f,0.f,0.f,0.f};
      #pragma unroll
      for (int kt = 0; kt < 8; ++kt){
        short8 af = *(const short8*)(Hc + jc*512 + ((kt*64 + q*16) ^ ((jc&7)<<4)));
        if (kt < 6){
          a00 = __builtin_amdgcn_mfma_f32_16x16x32_bf16(af, Wf[1][0][kt], a00, 0,0,0);
          a01 = __builtin_amdgcn_mfma_f32_16x16x32_bf16(af, Wf[1][1][kt], a01, 0,0,0);
          a10 = __builtin_amdgcn_mfma_f32_16x16x32_bf16(af, Wf[3][0][kt], a10, 0,0,0);
          a11 = __builtin_amdgcn_mfma_f32_16x16x32_bf16(af, Wf[3][1][kt], a11, 0,0,0);
        } else {
          a00 = __builtin_amdgcn_mfma_f32_16x16x32_bf16(af, *(const short8*)&WL[kt-6][16 + 2*w+0][lane][0], a00, 0,0,0);
          a01 = __builtin_amdgcn_mfma_f32_16x16x32_bf16(af, *(const short8*)&WL[kt-6][16 + 2*w+1][lane][0], a01, 0,0,0);
          a10 = __builtin_amdgcn_mfma_f32_16x16x32_bf16(af, *(const short8*)&WL[kt-6][48 + 2*w+0][lane][0], a10, 0,0,0);
          a11 = __builtin_amdgcn_mfma_f32_16x16x32_bf16(af, *(const short8*)&WL[kt-6][48 + 2*w+1][lane][0], a11, 0,0,0);
        }
      }
      #pragma unroll
      for (int u2=0; u2<2; ++u2){
        #pragma unroll
        for (int r=0; r<4; ++r){
          int e = u2*4 + r;
          float zf = (u2 ? a01[r] : a00[r]) + bf2f((u16)(xf[e>>1] >> ((e&1)*16)));
          float zo = (u2 ? a11[r] : a10[r]) + bf2f((u16)(xo[e>>1] >> ((e&1)*16)));
          float cc = sigf(zf)*c[u2][r] + P[u2][r];
          c[u2][r] = cc;
          float h = sigf(zo)*tanhfast(cc);
          int b_ = q*4 + r;
          int u_ = (2*w+u2)*16 + jc;
          Hn[b_*256 + (((u_*2) ^ ((b_&7)<<4))>>1)] = f2bu(h);
          int len_r = (int)((lens >> (8*r)) & 255u);
          if (t < len_r){
            int row = dir ? (len_r-1-t) : t;
            out[((b_<<7)+row)*512 + dir*256 + u_] = h;
          }
        }
      }
    }
    __syncthreads();
    curoff ^= 8192;
  }
}

// ---------------- prefix sums over s ----------------
__global__ void k_csum(const float* __restrict__ out, float* __restrict__ csum){
  int gid = blockIdx.x*256 + threadIdx.x;   // 8192 = 16*512
  int b = gid >> 9, d = gid & 511;
  float run = 0.f;
  csum[(b*129)*512 + d] = 0.f;
  for (int s = 0; s < 128; ++s){
    run += out[((b<<7)+s)*512 + d];
    csum[(b*129 + s + 1)*512 + d] = run;
  }
}

// ---------------- per-position first/last classifier terms ----------------
__global__ void k_ac(const float* __restrict__ out, const float* __restrict__ clf_w,
                     float* __restrict__ A, float* __restrict__ Cm){
  int gid = blockIdx.x*256 + threadIdx.x;   // 20480 = 2048*10
  int bs = gid / 10, tag = gid % 10;
  const float* o  = out + bs*512;
  const float* w1 = clf_w + tag*1536;       // "first" block
  const float* w3 = w1 + 1024;              // "last" block
  float a=0.f, cc=0.f;
  for (int d = 0; d < 512; ++d){
    float vv = fmaxf(o[d], 0.f);
    a  = fmaf(vv, w1[d], a);
    cc = fmaf(vv, w3[d], cc);
  }
  A[gid] = a; Cm[gid] = cc;
}

// ---------------- window classifier: wave per (n,b) ----------------
__global__ void k_clf(const float* __restrict__ csum, const float* __restrict__ clf_w,
                      const float* __restrict__ clf_b, const float* __restrict__ A,
                      const float* __restrict__ Cm, float* __restrict__ dout){
  __shared__ float w2_l[NTAGS*512];
  int tid = threadIdx.x;
  for (int i = tid; i < NTAGS*512; i += 256){
    int tag = i >> 9, d = i & 511;
    w2_l[i] = clf_w[tag*1536 + 512 + d];    // "mean" block
  }
  __syncthreads();
  int qq = blockIdx.x*4 + (tid >> 6);       // 0..30847
  int lane = tid & 63;
  int n = qq >> 4, b = qq & 15;
  int rem = n, r = 1;
  while (rem >= 129 - r){ rem -= 129 - r; ++r; }
  int s0 = rem, s1 = s0 + r - 1;
  float invr = 1.0f / (float)r;
  int d0 = lane*8;
  const float* c0 = csum + (b*129 + s0    )*512 + d0;
  const float* c1 = csum + (b*129 + s0 + r)*512 + d0;
  float m[8];
  #pragma unroll
  for (int i=0;i<8;++i) m[i] = fmaxf((c1[i]-c0[i])*invr, 0.f);
  float p[10];
  #pragma unroll
  for (int tag=0; tag<NTAGS; ++tag){
    const float* wv = w2_l + tag*512 + d0;
    float s = 0.f;
    #pragma unroll
    for (int i=0;i<8;++i) s = fmaf(m[i], wv[i], s);
    #pragma unroll
    for (int off=32; off>=1; off>>=1) s += __shfl_xor(s, off);
    p[tag] = s;
  }
  if (lane == 0){
    #pragma unroll
    for (int tag=0; tag<NTAGS; ++tag){
      float vv = p[tag] + A[(b*128+s0)*10+tag] + Cm[(b*128+s1)*10+tag] + clf_b[tag];
      dout[b*(NTAGS*NWIN) + tag*NWIN + n] = vv;
    }
  }
}

extern "C" void kernel_launch(void* const* d_in, const int* in_sizes, int n_in,
                              void* d_out, int out_size, void* d_ws, size_t ws_size,
                              hipStream_t stream){
  (void)in_sizes; (void)n_in; (void)out_size; (void)ws_size;
  const float* emb      = (const float*)d_in[0];
  const float* char_emb = (const float*)d_in[1];
  const float* c_wih_f  = (const float*)d_in[2];
  const float* c_whh_f  = (const float*)d_in[3];
  const float* c_b_f    = (const float*)d_in[4];
  const float* c_wih_b  = (const float*)d_in[5];
  const float* c_whh_b  = (const float*)d_in[6];
  const float* c_b_b    = (const float*)d_in[7];
  const float* w_wih_f  = (const float*)d_in[8];
  const float* w_whh_f  = (const float*)d_in[9];
  const float* w_b_f    = (const float*)d_in[10];
  const float* w_wih_b  = (const float*)d_in[11];
  const float* w_whh_b  = (const float*)d_in[12];
  const float* w_b_b    = (const float*)d_in[13];
  const float* clf_w    = (const float*)d_in[14];
  const float* clf_b    = (const float*)d_in[15];
  const int* sentences  = (const int*)d_in[16];
  const int* slens      = (const int*)d_in[17];
  const int* wchars     = (const int*)d_in[18];
  const int* wlens      = (const int*)d_in[19];

  float* ws   = (float*)d_ws;
  float* x    = ws;                       // 819,200 f
  u16*  xgT   = (u16*)(ws + 819200);      // 4,194,304 u16 = 2,097,152 f
  float* outb = ws + 2916352;             // 1,048,576 f
  float* csum = ws + 3964928;             // 1,056,768 f
  float* A    = ws + 5021696;             // 20,480 f
  float* Cm   = ws + 5042176;             // 20,480 f

  hipMemsetAsync(outb, 0, (size_t)2048*512*sizeof(float), stream);
  k_embed<<<2048, 256, 0, stream>>>(emb, sentences, x);
  k_char<<<dim3(512,2), 256, 0, stream>>>(char_emb, c_wih_f, c_whh_f, c_b_f,
                                          c_wih_b, c_whh_b, c_b_b,
                                          wchars, wlens, slens, x);
  k_wxg<<<dim3(32,32), 256, 0, stream>>>(x, w_wih_f, w_wih_b, w_b_f, w_b_b, slens, xgT);
  k_wlstm4<<<2, 512, 0, stream>>>(w_whh_f, w_whh_b, xgT, slens, outb);
  k_csum<<<32, 256, 0, stream>>>(outb, csum);
  k_ac<<<80, 256, 0, stream>>>(outb, clf_w, A, Cm);
  k_clf<<<7712, 256, 0, stream>>>(csum, clf_w, clf_b, A, Cm, (float*)d_out);
}

// Round 5
// 1146.057 us; speedup vs baseline: 1.0315x; 1.0220x over previous
//
#include <hip/hip_runtime.h>
#include <math.h>

typedef unsigned int u32;
typedef unsigned short u16;
typedef __attribute__((ext_vector_type(8))) short short8;
typedef __attribute__((ext_vector_type(4))) float f32x4;
typedef __attribute__((ext_vector_type(4))) u32 u32x4;

#define NB 16
#define NS 128
#define NTW 16
#define NEDIM 300
#define NCED 50
#define NCH 50
#define NTAGS 10
#define XDIM 400
#define NWIN 1928

__device__ __forceinline__ float sigf(float x){ return 1.0f/(1.0f+__expf(-x)); }
__device__ __forceinline__ float tanhfast(float x){
  float e = __expf(2.0f*x);
  return 1.0f - 2.0f/(e + 1.0f);
}
__device__ __forceinline__ u16 f2bu(float f){
  u32 u = __float_as_uint(f);
  return (u16)((u + 0x7fffu + ((u>>16)&1u))>>16);
}
__device__ __forceinline__ float bf2f(u16 x){ return __uint_as_float(((u32)x)<<16); }

// ---------------- embedding gather: x[:, 0:300] ----------------
__global__ void k_embed(const float* __restrict__ emb, const int* __restrict__ sent,
                        float* __restrict__ x){
  int n = blockIdx.x;                       // 0..2047 (b*128+s)
  int row = sent[n];
  const float* src = emb + (size_t)row*NEDIM;
  float* dst = x + (size_t)n*XDIM;
  for (int d = threadIdx.x; d < NEDIM; d += blockDim.x) dst[d] = src[d];
}

// ---------------- char BiLSTM (final hidden only) -> x[:, 300:400] ----------------
__global__ void k_char(const float* __restrict__ char_emb,
                       const float* __restrict__ wih_f, const float* __restrict__ whh_f, const float* __restrict__ b_f,
                       const float* __restrict__ wih_b, const float* __restrict__ whh_b, const float* __restrict__ b_b,
                       const int* __restrict__ wchars, const int* __restrict__ wlens,
                       const int* __restrict__ slens, float* __restrict__ x){
  const int dir = blockIdx.y;
  const int tid = threadIdx.x;
  __shared__ u16 wih_l[200*NCED];
  __shared__ u16 whh_l[200*NCED];
  __shared__ float z_l[200];
  __shared__ float h_l[NCH];
  const float* wih = dir ? wih_b : wih_f;
  const float* whh = dir ? whh_b : whh_f;
  const float* bp  = dir ? b_b   : b_f;
  for (int i = tid; i < 200*NCED; i += 256){
    wih_l[i] = f2bu(wih[i]);
    whh_l[i] = f2bu(whh[i]);
  }
  float bias = (tid < 200) ? bp[tid] : 0.f;
  __syncthreads();
  for (int w = 0; w < 4; ++w){
    int n = blockIdx.x*4 + w;
    int b = n >> 7, s = n & 127;
    int len = wlens[n];                    // in [1,16]
    float c = 0.f, hcur = 0.f;
    if (tid < NCH) h_l[tid] = 0.f;
    __syncthreads();
    for (int t = 0; t < len; ++t){
      int tt = dir ? (len-1-t) : t;
      int ch = wchars[n*NTW + tt];
      if (tid < 200){
        const float* xe = char_emb + ch*NCED;
        const u16* wr = wih_l + tid*NCED;
        const u16* ur = whh_l + tid*NCED;
        float acc = bias;
        #pragma unroll 10
        for (int k = 0; k < NCED; ++k){
          float wv = __uint_as_float(((u32)wr[k])<<16);
          float uv = __uint_as_float(((u32)ur[k])<<16);
          acc += wv*xe[k] + uv*h_l[k];
        }
        z_l[tid] = acc;
      }
      __syncthreads();
      if (tid < NCH){
        float gi = sigf(z_l[tid]);
        float gf = sigf(z_l[NCH+tid]);
        float gg = tanhf(z_l[2*NCH+tid]);
        float go = sigf(z_l[3*NCH+tid]);
        c = gf*c + gi*gg;
        hcur = go*tanhf(c);
        h_l[tid] = hcur;
      }
      __syncthreads();
    }
    if (tid < NCH){
      float v = (s < slens[b]) ? hcur : 0.f;   // pad_sequence zeroing
      x[(size_t)n*XDIM + NEDIM + dir*NCH + tid] = v;
    }
  }
}

// ---------------- xg = bf16(x @ wih^T + b) written in MFMA-fragment/t-major layout ----
__global__ void k_wxg(const float* __restrict__ x,
                      const float* __restrict__ wih_f, const float* __restrict__ wih_b,
                      const float* __restrict__ bw_f, const float* __restrict__ bw_b,
                      const int* __restrict__ slens,
                      u16* __restrict__ xgT){
  __shared__ float As[16][65];
  __shared__ float Bs[16][65];
  int tid = threadIdx.x;
  int tx = tid & 15, ty = tid >> 4;
  int n0 = blockIdx.x * 64;        // output col (dir*1024 + j)
  int m0 = blockIdx.y * 64;        // row (b*128+s)
  int dir = n0 >> 10;
  int j0  = n0 & 1023;
  const float* wih = dir ? wih_b : wih_f;
  const float* bw  = dir ? bw_b  : bw_f;
  float acc[4][4] = {};
  for (int k0 = 0; k0 < 400; k0 += 16){
    #pragma unroll
    for (int i = 0; i < 4; ++i){
      int e = tid + i*256;
      int kk = e & 15, m = e >> 4;
      As[kk][m] = x[(m0+m)*XDIM + k0 + kk];
      Bs[kk][m] = wih[(j0+m)*XDIM + k0 + kk];
    }
    __syncthreads();
    #pragma unroll
    for (int kk = 0; kk < 16; ++kk){
      float av[4], bv[4];
      #pragma unroll
      for (int i=0;i<4;++i) av[i] = As[kk][ty*4+i];
      #pragma unroll
      for (int j=0;j<4;++j) bv[j] = Bs[kk][tx*4+j];
      #pragma unroll
      for (int i=0;i<4;++i)
        #pragma unroll
        for (int j=0;j<4;++j) acc[i][j] = fmaf(av[i], bv[j], acc[i][j]);
    }
    __syncthreads();
  }
  int b_ = m0 >> 7;                 // batch, constant per block
  int len = slens[b_];
  int q_ = b_ >> 2, r_ = b_ & 3;
  #pragma unroll
  for (int i=0;i<4;++i){
    int m = m0 + ty*4 + i;
    int row = m & 127;
    int t = dir ? (len-1-row) : row;
    if (t >= 0){
      #pragma unroll
      for (int j=0;j<4;++j){
        int jj = j0 + tx*4 + j;          // j within dir, 0..1023
        float v = acc[i][j] + bw[jj];
        int g = jj >> 8, u = jj & 255;
        int ut = u >> 4, jc_ = u & 15;
        int w_ = ut >> 1, u2_ = ut & 1;
        int p_ = g & 1, gg_ = g >> 1;
        int tid_ = w_*64 + q_*16 + jc_;
        size_t e = ((size_t)((dir<<7) + t)*512 + tid_)*32 + p_*16 + gg_*8 + u2_*4 + r_;
        xgT[e] = f2bu(v);
      }
    }
  }
}

// ---------------- pack whh K-tiles 6,7 into MFMA-B-fragment order ----------------
// slot = p*8 + gg*4 + u2*2 + kt2; region per (dir,w): 16 slots x 64 lanes x 16B.
__global__ void k_wfrag(const float* __restrict__ whh_f, const float* __restrict__ whh_b,
                        u32* __restrict__ Wst){
  int gid = blockIdx.x*256 + threadIdx.x;   // 0..16383
  int lane = gid & 63;
  int slot = (gid >> 6) & 15;
  int w    = (gid >> 10) & 7;
  int dir  = gid >> 13;
  int p   = slot >> 3;
  int gg  = (slot >> 2) & 1;
  int u2  = (slot >> 1) & 1;
  int kt2 = slot & 1;
  int gate = gg*2 + p;
  int q = lane >> 4, jc = lane & 15;
  int j = gate*256 + (2*w + u2)*16 + jc;
  int k0 = (6 + kt2)*32 + q*8;
  const float* wr = (dir ? whh_b : whh_f) + (size_t)j*256 + k0;
  u32* dst = Wst + ((size_t)(((dir*8 + w)*16 + slot)*64 + lane))*4;
  #pragma unroll
  for (int e2 = 0; e2 < 4; ++e2){
    dst[e2] = ((u32)f2bu(wr[2*e2+1]) << 16) | f2bu(wr[2*e2]);
  }
}

// ---------------- word BiLSTM recurrence: 2 blocks (one per dir) ----------------
// 8 waves; wave w owns u-tiles {2w,2w+1} x 4 gates. Weight split per wave:
//   kt 0-3: VGPR-resident (32 frags = 128 regs)   <- fits 256-reg budget
//   kt 4-5: LDS (128 KB)
//   kt 6-7: streamed from L2-resident packed buffer each step (same addr every step)
// H double-buffered in LDS. One barrier per step.
__global__ __launch_bounds__(512, 2) void k_wlstm5(
    const float* __restrict__ whh_f, const float* __restrict__ whh_b,
    const u16* __restrict__ xgT, const u32* __restrict__ Wst,
    const int* __restrict__ slens, float* __restrict__ out){
  const int dir  = blockIdx.x;
  const int tid  = threadIdx.x;
  const int lane = tid & 63;
  const int w    = tid >> 6;        // wave 0..7
  const int q    = lane >> 4;       // 0..3
  const int jc   = lane & 15;

  __shared__ __align__(16) u32 WL[2][64][64][4];   // 128 KB: K-tiles 4,5
  __shared__ __align__(16) u16 Hs[2][16][256];     // 16 KB: H double-buffered

  const float* whh = dir ? whh_b : whh_f;

  u32 lens = 0;
  #pragma unroll
  for (int r=0;r<4;++r) lens |= ((u32)slens[q*4+r]) << (8*r);

  // ---- VGPR weights: kt 0..3 ----
  short8 Wf[4][2][4];
  #pragma unroll
  for (int g=0; g<4; ++g){
    #pragma unroll
    for (int u2=0; u2<2; ++u2){
      int j = g*256 + (2*w+u2)*16 + jc;
      const float* wr = whh + (size_t)j*256;
      #pragma unroll
      for (int kt=0; kt<4; ++kt){
        int k0 = kt*32 + q*8;
        f32x4 w0 = *(const f32x4*)(wr + k0);
        f32x4 w1 = *(const f32x4*)(wr + k0 + 4);
        short8 s;
        s[0]=(short)f2bu(w0[0]); s[1]=(short)f2bu(w0[1]);
        s[2]=(short)f2bu(w0[2]); s[3]=(short)f2bu(w0[3]);
        s[4]=(short)f2bu(w1[0]); s[5]=(short)f2bu(w1[1]);
        s[6]=(short)f2bu(w1[2]); s[7]=(short)f2bu(w1[3]);
        Wf[g][u2][kt] = s;
      }
    }
  }

  // ---- LDS weights: kt 4,5 ----
  for (int idx = tid; idx < 2*64*64; idx += 512){
    int kt2 = idx >> 12; int rem = idx & 4095;
    int jt = rem >> 6;   int ln = rem & 63;
    int g = jt >> 4, ut = jt & 15;
    int j = g*256 + ut*16 + (ln & 15);
    int k0 = (4+kt2)*32 + (ln>>4)*8;
    const float* wr = whh + (size_t)j*256 + k0;
    f32x4 w0 = *(const f32x4*)(wr);
    f32x4 w1 = *(const f32x4*)(wr + 4);
    WL[kt2][jt][ln][0] = ((u32)f2bu(w0[1])<<16) | f2bu(w0[0]);
    WL[kt2][jt][ln][1] = ((u32)f2bu(w0[3])<<16) | f2bu(w0[2]);
    WL[kt2][jt][ln][2] = ((u32)f2bu(w1[1])<<16) | f2bu(w1[0]);
    WL[kt2][jt][ln][3] = ((u32)f2bu(w1[3])<<16) | f2bu(w1[2]);
  }

  for (int i = tid; i < 2048; i += 512) ((u32*)Hs[0])[i] = 0u;
  __syncthreads();

  float c[2][4] = {{0.f,0.f,0.f,0.f},{0.f,0.f,0.f,0.f}};
  float P[2][4];
  const u16* xbase = xgT + ((size_t)(dir*128)*512 + tid)*32;
  const u32x4* wsb = ((const u32x4*)Wst) + (size_t)(dir*8 + w)*16*64 + lane;
  u32 curoff = 0;

  #pragma clang loop unroll(disable)
  for (int t = 0; t < 128; ++t){
    const u16* xp = xbase + t*16384;

    const char* Hc = ((const char*)Hs) + curoff;
    u16* Hn = (u16*)(((char*)Hs) + (curoff ^ 8192));

    // ---- phase 0: gates i (0) and g (2) ----
    {
      // stream kt6,7 frags for this phase (slots 0..7); same address every step -> L2 hit
      u32x4 sf0 = wsb[0*64], sf1 = wsb[1*64], sf2 = wsb[2*64], sf3 = wsb[3*64];
      u32x4 sf4 = wsb[4*64], sf5 = wsb[5*64], sf6 = wsb[6*64], sf7 = wsb[7*64];
      u32x4 xi = *(const u32x4*)(xp);
      u32x4 xg = *(const u32x4*)(xp + 8);
      f32x4 a00={0.f,0.f,0.f,0.f}, a01={0.f,0.f,0.f,0.f};
      f32x4 a10={0.f,0.f,0.f,0.f}, a11={0.f,0.f,0.f,0.f};
      #pragma unroll
      for (int kt = 0; kt < 8; ++kt){
        short8 af = *(const short8*)(Hc + jc*512 + ((kt*64 + q*16) ^ ((jc&7)<<4)));
        if (kt < 4){
          a00 = __builtin_amdgcn_mfma_f32_16x16x32_bf16(af, Wf[0][0][kt], a00, 0,0,0);
          a01 = __builtin_amdgcn_mfma_f32_16x16x32_bf16(af, Wf[0][1][kt], a01, 0,0,0);
          a10 = __builtin_amdgcn_mfma_f32_16x16x32_bf16(af, Wf[2][0][kt], a10, 0,0,0);
          a11 = __builtin_amdgcn_mfma_f32_16x16x32_bf16(af, Wf[2][1][kt], a11, 0,0,0);
        } else if (kt < 6){
          a00 = __builtin_amdgcn_mfma_f32_16x16x32_bf16(af, *(const short8*)&WL[kt-4][ 0 + 2*w+0][lane][0], a00, 0,0,0);
          a01 = __builtin_amdgcn_mfma_f32_16x16x32_bf16(af, *(const short8*)&WL[kt-4][ 0 + 2*w+1][lane][0], a01, 0,0,0);
          a10 = __builtin_amdgcn_mfma_f32_16x16x32_bf16(af, *(const short8*)&WL[kt-4][32 + 2*w+0][lane][0], a10, 0,0,0);
          a11 = __builtin_amdgcn_mfma_f32_16x16x32_bf16(af, *(const short8*)&WL[kt-4][32 + 2*w+1][lane][0], a11, 0,0,0);
        } else if (kt == 6){
          a00 = __builtin_amdgcn_mfma_f32_16x16x32_bf16(af, *(const short8*)&sf0, a00, 0,0,0);
          a01 = __builtin_amdgcn_mfma_f32_16x16x32_bf16(af, *(const short8*)&sf2, a01, 0,0,0);
          a10 = __builtin_amdgcn_mfma_f32_16x16x32_bf16(af, *(const short8*)&sf4, a10, 0,0,0);
          a11 = __builtin_amdgcn_mfma_f32_16x16x32_bf16(af, *(const short8*)&sf6, a11, 0,0,0);
        } else {
          a00 = __builtin_amdgcn_mfma_f32_16x16x32_bf16(af, *(const short8*)&sf1, a00, 0,0,0);
          a01 = __builtin_amdgcn_mfma_f32_16x16x32_bf16(af, *(const short8*)&sf3, a01, 0,0,0);
          a10 = __builtin_amdgcn_mfma_f32_16x16x32_bf16(af, *(const short8*)&sf5, a10, 0,0,0);
          a11 = __builtin_amdgcn_mfma_f32_16x16x32_bf16(af, *(const short8*)&sf7, a11, 0,0,0);
        }
      }
      #pragma unroll
      for (int u2=0; u2<2; ++u2){
        #pragma unroll
        for (int r=0; r<4; ++r){
          int e = u2*4 + r;
          float zi = (u2 ? a01[r] : a00[r]) + bf2f((u16)(xi[e>>1] >> ((e&1)*16)));
          float zg = (u2 ? a11[r] : a10[r]) + bf2f((u16)(xg[e>>1] >> ((e&1)*16)));
          P[u2][r] = sigf(zi) * tanhfast(zg);
        }
      }
    }

    // ---- phase 1: gates f (1) and o (3) ----
    {
      u32x4 sf0 = wsb[ 8*64], sf1 = wsb[ 9*64], sf2 = wsb[10*64], sf3 = wsb[11*64];
      u32x4 sf4 = wsb[12*64], sf5 = wsb[13*64], sf6 = wsb[14*64], sf7 = wsb[15*64];
      u32x4 xf = *(const u32x4*)(xp + 16);
      u32x4 xo = *(const u32x4*)(xp + 24);
      f32x4 a00={0.f,0.f,0.f,0.f}, a01={0.f,0.f,0.f,0.f};
      f32x4 a10={0.f,0.f,0.f,0.f}, a11={0.f,0.f,0.f,0.f};
      #pragma unroll
      for (int kt = 0; kt < 8; ++kt){
        short8 af = *(const short8*)(Hc + jc*512 + ((kt*64 + q*16) ^ ((jc&7)<<4)));
        if (kt < 4){
          a00 = __builtin_amdgcn_mfma_f32_16x16x32_bf16(af, Wf[1][0][kt], a00, 0,0,0);
          a01 = __builtin_amdgcn_mfma_f32_16x16x32_bf16(af, Wf[1][1][kt], a01, 0,0,0);
          a10 = __builtin_amdgcn_mfma_f32_16x16x32_bf16(af, Wf[3][0][kt], a10, 0,0,0);
          a11 = __builtin_amdgcn_mfma_f32_16x16x32_bf16(af, Wf[3][1][kt], a11, 0,0,0);
        } else if (kt < 6){
          a00 = __builtin_amdgcn_mfma_f32_16x16x32_bf16(af, *(const short8*)&WL[kt-4][16 + 2*w+0][lane][0], a00, 0,0,0);
          a01 = __builtin_amdgcn_mfma_f32_16x16x32_bf16(af, *(const short8*)&WL[kt-4][16 + 2*w+1][lane][0], a01, 0,0,0);
          a10 = __builtin_amdgcn_mfma_f32_16x16x32_bf16(af, *(const short8*)&WL[kt-4][48 + 2*w+0][lane][0], a10, 0,0,0);
          a11 = __builtin_amdgcn_mfma_f32_16x16x32_bf16(af, *(const short8*)&WL[kt-4][48 + 2*w+1][lane][0], a11, 0,0,0);
        } else if (kt == 6){
          a00 = __builtin_amdgcn_mfma_f32_16x16x32_bf16(af, *(const short8*)&sf0, a00, 0,0,0);
          a01 = __builtin_amdgcn_mfma_f32_16x16x32_bf16(af, *(const short8*)&sf2, a01, 0,0,0);
          a10 = __builtin_amdgcn_mfma_f32_16x16x32_bf16(af, *(const short8*)&sf4, a10, 0,0,0);
          a11 = __builtin_amdgcn_mfma_f32_16x16x32_bf16(af, *(const short8*)&sf6, a11, 0,0,0);
        } else {
          a00 = __builtin_amdgcn_mfma_f32_16x16x32_bf16(af, *(const short8*)&sf1, a00, 0,0,0);
          a01 = __builtin_amdgcn_mfma_f32_16x16x32_bf16(af, *(const short8*)&sf3, a01, 0,0,0);
          a10 = __builtin_amdgcn_mfma_f32_16x16x32_bf16(af, *(const short8*)&sf5, a10, 0,0,0);
          a11 = __builtin_amdgcn_mfma_f32_16x16x32_bf16(af, *(const short8*)&sf7, a11, 0,0,0);
        }
      }
      #pragma unroll
      for (int u2=0; u2<2; ++u2){
        #pragma unroll
        for (int r=0; r<4; ++r){
          int e = u2*4 + r;
          float zf = (u2 ? a01[r] : a00[r]) + bf2f((u16)(xf[e>>1] >> ((e&1)*16)));
          float zo = (u2 ? a11[r] : a10[r]) + bf2f((u16)(xo[e>>1] >> ((e&1)*16)));
          float cc = sigf(zf)*c[u2][r] + P[u2][r];
          c[u2][r] = cc;
          float h = sigf(zo)*tanhfast(cc);
          int b_ = q*4 + r;
          int u_ = (2*w+u2)*16 + jc;
          Hn[b_*256 + (((u_*2) ^ ((b_&7)<<4))>>1)] = f2bu(h);
          int len_r = (int)((lens >> (8*r)) & 255u);
          if (t < len_r){
            int row = dir ? (len_r-1-t) : t;
            out[((b_<<7)+row)*512 + dir*256 + u_] = h;
          }
        }
      }
    }
    __syncthreads();
    curoff ^= 8192;
  }
}

// ---------------- prefix sums over s ----------------
__global__ void k_csum(const float* __restrict__ out, float* __restrict__ csum){
  int gid = blockIdx.x*256 + threadIdx.x;   // 8192 = 16*512
  int b = gid >> 9, d = gid & 511;
  float run = 0.f;
  csum[(b*129)*512 + d] = 0.f;
  for (int s = 0; s < 128; ++s){
    run += out[((b<<7)+s)*512 + d];
    csum[(b*129 + s + 1)*512 + d] = run;
  }
}

// ---------------- per-position first/last classifier terms ----------------
__global__ void k_ac(const float* __restrict__ out, const float* __restrict__ clf_w,
                     float* __restrict__ A, float* __restrict__ Cm){
  int gid = blockIdx.x*256 + threadIdx.x;   // 20480 = 2048*10
  int bs = gid / 10, tag = gid % 10;
  const float* o  = out + bs*512;
  const float* w1 = clf_w + tag*1536;       // "first" block
  const float* w3 = w1 + 1024;              // "last" block
  float a=0.f, cc=0.f;
  for (int d = 0; d < 512; ++d){
    float vv = fmaxf(o[d], 0.f);
    a  = fmaf(vv, w1[d], a);
    cc = fmaf(vv, w3[d], cc);
  }
  A[gid] = a; Cm[gid] = cc;
}

// ---------------- window classifier: wave per (n,b) ----------------
__global__ void k_clf(const float* __restrict__ csum, const float* __restrict__ clf_w,
                      const float* __restrict__ clf_b, const float* __restrict__ A,
                      const float* __restrict__ Cm, float* __restrict__ dout){
  __shared__ float w2_l[NTAGS*512];
  int tid = threadIdx.x;
  for (int i = tid; i < NTAGS*512; i += 256){
    int tag = i >> 9, d = i & 511;
    w2_l[i] = clf_w[tag*1536 + 512 + d];    // "mean" block
  }
  __syncthreads();
  int qq = blockIdx.x*4 + (tid >> 6);       // 0..30847
  int lane = tid & 63;
  int n = qq >> 4, b = qq & 15;
  int rem = n, r = 1;
  while (rem >= 129 - r){ rem -= 129 - r; ++r; }
  int s0 = rem, s1 = s0 + r - 1;
  float invr = 1.0f / (float)r;
  int d0 = lane*8;
  const float* c0 = csum + (b*129 + s0    )*512 + d0;
  const float* c1 = csum + (b*129 + s0 + r)*512 + d0;
  float m[8];
  #pragma unroll
  for (int i=0;i<8;++i) m[i] = fmaxf((c1[i]-c0[i])*invr, 0.f);
  float p[10];
  #pragma unroll
  for (int tag=0; tag<NTAGS; ++tag){
    const float* wv = w2_l + tag*512 + d0;
    float s = 0.f;
    #pragma unroll
    for (int i=0;i<8;++i) s = fmaf(m[i], wv[i], s);
    #pragma unroll
    for (int off=32; off>=1; off>>=1) s += __shfl_xor(s, off);
    p[tag] = s;
  }
  if (lane == 0){
    #pragma unroll
    for (int tag=0; tag<NTAGS; ++tag){
      float vv = p[tag] + A[(b*128+s0)*10+tag] + Cm[(b*128+s1)*10+tag] + clf_b[tag];
      dout[b*(NTAGS*NWIN) + tag*NWIN + n] = vv;
    }
  }
}

extern "C" void kernel_launch(void* const* d_in, const int* in_sizes, int n_in,
                              void* d_out, int out_size, void* d_ws, size_t ws_size,
                              hipStream_t stream){
  (void)in_sizes; (void)n_in; (void)out_size; (void)ws_size;
  const float* emb      = (const float*)d_in[0];
  const float* char_emb = (const float*)d_in[1];
  const float* c_wih_f  = (const float*)d_in[2];
  const float* c_whh_f  = (const float*)d_in[3];
  const float* c_b_f    = (const float*)d_in[4];
  const float* c_wih_b  = (const float*)d_in[5];
  const float* c_whh_b  = (const float*)d_in[6];
  const float* c_b_b    = (const float*)d_in[7];
  const float* w_wih_f  = (const float*)d_in[8];
  const float* w_whh_f  = (const float*)d_in[9];
  const float* w_b_f    = (const float*)d_in[10];
  const float* w_wih_b  = (const float*)d_in[11];
  const float* w_whh_b  = (const float*)d_in[12];
  const float* w_b_b    = (const float*)d_in[13];
  const float* clf_w    = (const float*)d_in[14];
  const float* clf_b    = (const float*)d_in[15];
  const int* sentences  = (const int*)d_in[16];
  const int* slens      = (const int*)d_in[17];
  const int* wchars     = (const int*)d_in[18];
  const int* wlens      = (const int*)d_in[19];

  float* ws   = (float*)d_ws;
  float* x    = ws;                       // 819,200 f
  u16*  xgT   = (u16*)(ws + 819200);      // 4,194,304 u16 = 2,097,152 f
  float* outb = ws + 2916352;             // 1,048,576 f
  float* csum = ws + 3964928;             // 1,056,768 f
  float* A    = ws + 5021696;             // 20,480 f
  float* Cm   = ws + 5042176;             // 20,480 f
  u32*  Wst   = (u32*)(ws + 5062656);     // 65,536 u32 (256 KB packed kt6,7 frags)

  hipMemsetAsync(outb, 0, (size_t)2048*512*sizeof(float), stream);
  k_embed<<<2048, 256, 0, stream>>>(emb, sentences, x);
  k_wfrag<<<64, 256, 0, stream>>>(w_whh_f, w_whh_b, Wst);
  k_char<<<dim3(512,2), 256, 0, stream>>>(char_emb, c_wih_f, c_whh_f, c_b_f,
                                          c_wih_b, c_whh_b, c_b_b,
                                          wchars, wlens, slens, x);
  k_wxg<<<dim3(32,32), 256, 0, stream>>>(x, w_wih_f, w_wih_b, w_b_f, w_b_b, slens, xgT);
  k_wlstm5<<<2, 512, 0, stream>>>(w_whh_f, w_whh_b, xgT, Wst, slens, outb);
  k_csum<<<32, 256, 0, stream>>>(outb, csum);
  k_ac<<<80, 256, 0, stream>>>(outb, clf_w, A, Cm);
  k_clf<<<7712, 256, 0, stream>>>(csum, clf_w, clf_b, A, Cm, (float*)d_out);
}